// Round 6
// baseline (912.851 us; speedup 1.0000x reference)
//
#include <hip/hip_runtime.h>

// ---------------- problem constants ----------------
#define BATCH 2
#define SEQ   2048
#define DIM   1024
#define NH    16
#define DK    64
#define SCALE_F 0.125f
#define MASKED  -2e30f
#define MINIT   -1e30f

typedef __attribute__((ext_vector_type(4))) float f4;
typedef __attribute__((ext_vector_type(4))) float f32x4;
typedef __attribute__((ext_vector_type(8))) short s16x8;
typedef __attribute__((ext_vector_type(4))) int  i32x4;
typedef __attribute__((ext_vector_type(4))) unsigned short u16x4;

__device__ __forceinline__ float bf2f(unsigned short u){ return __uint_as_float(((unsigned)u) << 16); }
__device__ __forceinline__ unsigned short f2bf(float f){
  unsigned u = __float_as_uint(f);
  u += 0x7FFFu + ((u >> 16) & 1u);
  return (unsigned short)(u >> 16);
}

// async global->LDS, 16B per lane. LDS dest = wave-uniform base + lane*16.
#define ASYNC_LDS16(g, l) \
  __builtin_amdgcn_global_load_lds((const __attribute__((address_space(1))) void*)(g), \
                                   (__attribute__((address_space(3))) void*)(l), 16, 0, 0)

// ---------------- cast fp32 -> bf16 (vectorized) ----------------
__global__ __launch_bounds__(256) void cast_bf16_kernel(const float* __restrict__ in,
                                                        unsigned short* __restrict__ out, int n){
  int i = (blockIdx.x * 256 + threadIdx.x) * 4;
  if (i < n){
    f4 v = *(const f4*)&in[i];
    u16x4 o = { f2bf(v[0]), f2bf(v[1]), f2bf(v[2]), f2bf(v[3]) };
    *(u16x4*)&out[i] = o;
  }
}

// ---------------- batched transpose + cast: W (K x DIM fp32) -> Wt (DIM x K bf16) ----------------
struct TCP { const float* w[12]; unsigned short* wt[12]; };
__global__ __launch_bounds__(256) void transpose_cast_b(TCP P, int K){
  const float* W = P.w[blockIdx.z];
  unsigned short* Wt = P.wt[blockIdx.z];
  __shared__ float tile[32][33];
  int x = threadIdx.x & 31, y = threadIdx.x >> 5;
  int bc = blockIdx.x << 5;   // over N (=DIM)
  int br = blockIdx.y << 5;   // over K
  #pragma unroll
  for (int yy = y; yy < 32; yy += 8)
    tile[yy][x] = W[(size_t)(br + yy) * DIM + bc + x];
  __syncthreads();
  #pragma unroll
  for (int yy = y; yy < 32; yy += 8)
    Wt[(size_t)(bc + yy) * K + br + x] = f2bf(tile[x][yy]);
}

// ---------------- gc extraction: x[:, ::64] -> bf16, padded to 128 rows ----------------
__global__ __launch_bounds__(256) void gc_extract(const float* __restrict__ x,
                                                  unsigned short* __restrict__ gcb){
  int row = blockIdx.x;         // 0..127
  int t = threadIdx.x;
  unsigned short* dst = gcb + (size_t)row * DIM;
  if (row < BATCH * 32){
    int b = row >> 5, g = row & 31;
    const float* src = x + ((size_t)b * SEQ + (size_t)g * 64) * DIM;
    f4 v = *(const f4*)&src[t * 4];
    u16x4 o = { f2bf(v[0]), f2bf(v[1]), f2bf(v[2]), f2bf(v[3]) };
    *(u16x4*)&dst[t * 4] = o;
  } else {
    u16x4 z = { 0, 0, 0, 0 };
    *(u16x4*)&dst[t * 4] = z;
  }
}

// ---------------- GEMM output descriptors ----------------
struct GOut { unsigned short* ob; float* of; const float* bias; int ld; int tr; };
struct GOuts { GOut d[4]; };

// ---------------- 128-tile bf16 MFMA GEMM (narrow/small shapes) ----------------
// Counted-vmcnt dbuf pipeline, k-chunk XOR swizzle (src-side + read-side).
template<int BN>
__global__ __launch_bounds__(256) void gemm_bf16(
    const unsigned short* __restrict__ A, const unsigned short* __restrict__ Bt,
    GOuts descs, int K)
{
  constexpr int NF = BN / 32;                 // n-frags per wave
  __shared__ __align__(16) unsigned short As[2][128 * 32];
  __shared__ __align__(16) unsigned short Bs[2][BN * 32];
  const int tid = threadIdx.x;
  const int lane = tid & 63;
  const int w = tid >> 6;
  const int wr = w >> 1, wc = w & 1;
  const int gx = gridDim.x;
  const int nwg = gx * gridDim.y;             // always % 8 == 0
  const int orig = blockIdx.y * gx + blockIdx.x;
  const int swz = (orig & 7) * (nwg >> 3) + (orig >> 3);
  const int tx = swz % gx, ty = swz / gx;
  const int tm = ty << 7, tn = tx * BN;
  const GOut dsc = descs.d[tn >> 10];
  const int trans = dsc.tr;

  const int r0 = tid >> 2;
  const int ksw = (((tid & 3) ^ ((tid >> 3) & 3)) << 3);   // pre-swizzled k-offset (elems)
  const unsigned short* Ag0 = A + (size_t)(tm + r0) * K + ksw;
  const unsigned short* Ag1 = A + (size_t)(tm + r0 + 64) * K + ksw;
  const unsigned short* Bg0 = Bt + (size_t)(tn + r0) * K + ksw;
  const unsigned short* Bg1 = Bt + (size_t)(tn + r0 + 64) * K + ksw;  // BN==128 only

  f32x4 acc[4][NF];
  #pragma unroll
  for (int m = 0; m < 4; ++m)
    #pragma unroll
    for (int n = 0; n < NF; ++n) acc[m][n] = (f32x4){0.f, 0.f, 0.f, 0.f};

  const int fr = lane & 15, fg = lane >> 4;
  const int kro = ((fg ^ ((fr >> 1) & 3)) << 3);           // swizzled read chunk (elems)

  auto STAGE = [&](int buf, int t){
    const int kk = t * 32;
    ASYNC_LDS16(Ag0 + kk, &As[buf][w * 512]);
    ASYNC_LDS16(Ag1 + kk, &As[buf][w * 512 + 2048]);
    ASYNC_LDS16(Bg0 + kk, &Bs[buf][w * 512]);
    if constexpr (BN == 128) ASYNC_LDS16(Bg1 + kk, &Bs[buf][w * 512 + 2048]);
  };
  auto COMPUTE = [&](int buf){
    s16x8 af[4], bfv[NF];
    #pragma unroll
    for (int m = 0; m < 4; ++m)
      af[m] = *(const s16x8*)&As[buf][(wr * 64 + m * 16 + fr) * 32 + kro];
    #pragma unroll
    for (int n = 0; n < NF; ++n)
      bfv[n] = *(const s16x8*)&Bs[buf][(wc * (BN / 2) + n * 16 + fr) * 32 + kro];
    if (trans){
      #pragma unroll
      for (int m = 0; m < 4; ++m)
        #pragma unroll
        for (int n = 0; n < NF; ++n)
          acc[m][n] = __builtin_amdgcn_mfma_f32_16x16x32_bf16(bfv[n], af[m], acc[m][n], 0, 0, 0);
    } else {
      #pragma unroll
      for (int m = 0; m < 4; ++m)
        #pragma unroll
        for (int n = 0; n < NF; ++n)
          acc[m][n] = __builtin_amdgcn_mfma_f32_16x16x32_bf16(af[m], bfv[n], acc[m][n], 0, 0, 0);
    }
  };

  const int nt = K >> 5;                       // K/32 tiles, always >= 2
  STAGE(0, 0);
  STAGE(1, 1);
  for (int t = 0; t < nt - 1; ++t){
    const int cur = t & 1;
    if constexpr (BN == 128) asm volatile("s_waitcnt vmcnt(4)" ::: "memory");
    else                     asm volatile("s_waitcnt vmcnt(3)" ::: "memory");
    __builtin_amdgcn_s_barrier();
    __builtin_amdgcn_sched_barrier(0);        // no ds_read above the barrier
    COMPUTE(cur);
    __builtin_amdgcn_sched_barrier(0);        // MFMA/ds_read stay before barrier
    __builtin_amdgcn_s_barrier();
    __builtin_amdgcn_sched_barrier(0);        // no stage-write above the barrier
    if (t + 2 < nt) STAGE(cur, t + 2);
  }
  asm volatile("s_waitcnt vmcnt(0)" ::: "memory");
  __builtin_amdgcn_s_barrier();
  __builtin_amdgcn_sched_barrier(0);
  COMPUTE((nt - 1) & 1);

  // epilogue
  #pragma unroll
  for (int m = 0; m < 4; ++m){
    #pragma unroll
    for (int n = 0; n < NF; ++n){
      if (!trans){
        int cl = (tn + wc * (BN / 2) + n * 16 + fr) & 1023;   // col within this output
        float bv = dsc.bias ? dsc.bias[cl] : 0.f;
        #pragma unroll
        for (int r = 0; r < 4; ++r){
          int row = tm + wr * 64 + m * 16 + fg * 4 + r;
          float v = acc[m][n][r] + bv;
          if (dsc.of) dsc.of[(size_t)row * dsc.ld + cl] = v;
          if (dsc.ob) dsc.ob[(size_t)row * dsc.ld + cl] = f2bf(v);
        }
      } else {
        int colT = tm + wr * 64 + m * 16 + fr;                // token
        #pragma unroll
        for (int r = 0; r < 4; ++r){
          int dl = (tn + wc * (BN / 2) + n * 16 + fg * 4 + r) & 1023;  // d_out within output
          float v = acc[m][n][r] + (dsc.bias ? dsc.bias[dl] : 0.f);
          dsc.ob[(size_t)dl * dsc.ld + colT] = f2bf(v);
        }
      }
    }
  }
}

// ---------------- 256-tile bf16 MFMA GEMM (big fused shapes) ----------------
// 256x256 tile, BK=64, 8 waves (2x4), 128 KB LDS dbuf, counted vmcnt(8).
// LDS rows are 64 elems (128 B): 16B-chunk c of row R holds logical chunk c^(R&7)
// (pre-swizzled global source, swizzled ds_read) -> 2 lanes/slot per quarter-wave (free).
__global__ __launch_bounds__(512, 2) void gemm256(
    const unsigned short* __restrict__ A, const unsigned short* __restrict__ Bt,
    GOuts descs, int K)
{
  __shared__ __align__(16) unsigned short As[2][256 * 64];
  __shared__ __align__(16) unsigned short Bs[2][256 * 64];
  const int tid = threadIdx.x;            // 0..511
  const int lane = tid & 63;
  const int w = tid >> 6;                 // 0..7
  const int wr = w >> 2, wc = w & 3;      // 2 x 4 wave grid
  const int gx = gridDim.x;
  const int nwg = gx * gridDim.y;         // % 8 == 0
  const int orig = blockIdx.y * gx + blockIdx.x;
  const int swz = (orig & 7) * (nwg >> 3) + (orig >> 3);
  const int tx = swz % gx, ty = swz / gx;
  const int tm = ty << 8, tn = tx << 8;
  const GOut dsc = descs.d[tn >> 10];
  const int trans = dsc.tr;

  // staging: segment s = w*4+i covers rows s*8..s*8+7; lane -> row s*8+(lane>>3), phys chunk lane&7
  const int sr = lane >> 3;
  const int klog = (((lane & 7) ^ sr) << 3);   // logical k elem offset (pre-swizzle)
  const unsigned short* Agp[4];
  const unsigned short* Bgp[4];
  #pragma unroll
  for (int i = 0; i < 4; ++i){
    const int s = w * 4 + i;
    Agp[i] = A + (size_t)(tm + s * 8 + sr) * K + klog;
    Bgp[i] = Bt + (size_t)(tn + s * 8 + sr) * K + klog;
  }

  f32x4 acc[8][4];
  #pragma unroll
  for (int m = 0; m < 8; ++m)
    #pragma unroll
    for (int n = 0; n < 4; ++n) acc[m][n] = (f32x4){0.f, 0.f, 0.f, 0.f};

  const int fr = lane & 15, fg = lane >> 4;

  auto STAGE = [&](int buf, int t){
    const int kk = t * 64;
    #pragma unroll
    for (int i = 0; i < 4; ++i){
      ASYNC_LDS16(Agp[i] + kk, &As[buf][(w * 4 + i) * 512]);
      ASYNC_LDS16(Bgp[i] + kk, &Bs[buf][(w * 4 + i) * 512]);
    }
  };
  auto COMPUTE = [&](int buf){
    #pragma unroll
    for (int ks = 0; ks < 2; ++ks){
      const int rc = (((ks * 4 + fg) ^ (fr & 7)) << 3);   // swizzled read chunk
      s16x8 af[8], bfv[4];
      #pragma unroll
      for (int m = 0; m < 8; ++m)
        af[m] = *(const s16x8*)&As[buf][(wr * 128 + m * 16 + fr) * 64 + rc];
      #pragma unroll
      for (int n = 0; n < 4; ++n)
        bfv[n] = *(const s16x8*)&Bs[buf][(wc * 64 + n * 16 + fr) * 64 + rc];
      if (trans){
        #pragma unroll
        for (int m = 0; m < 8; ++m)
          #pragma unroll
          for (int n = 0; n < 4; ++n)
            acc[m][n] = __builtin_amdgcn_mfma_f32_16x16x32_bf16(bfv[n], af[m], acc[m][n], 0, 0, 0);
      } else {
        #pragma unroll
        for (int m = 0; m < 8; ++m)
          #pragma unroll
          for (int n = 0; n < 4; ++n)
            acc[m][n] = __builtin_amdgcn_mfma_f32_16x16x32_bf16(af[m], bfv[n], acc[m][n], 0, 0, 0);
      }
    }
  };

  const int nt = K >> 6;                   // K/64, >= 2
  STAGE(0, 0);
  STAGE(1, 1);
  for (int t = 0; t < nt - 1; ++t){
    const int cur = t & 1;
    asm volatile("s_waitcnt vmcnt(8)" ::: "memory");
    __builtin_amdgcn_s_barrier();
    __builtin_amdgcn_sched_barrier(0);
    COMPUTE(cur);
    __builtin_amdgcn_sched_barrier(0);
    __builtin_amdgcn_s_barrier();
    __builtin_amdgcn_sched_barrier(0);
    if (t + 2 < nt) STAGE(cur, t + 2);
  }
  asm volatile("s_waitcnt vmcnt(0)" ::: "memory");
  __builtin_amdgcn_s_barrier();
  __builtin_amdgcn_sched_barrier(0);
  COMPUTE((nt - 1) & 1);

  // epilogue
  #pragma unroll
  for (int m = 0; m < 8; ++m){
    #pragma unroll
    for (int n = 0; n < 4; ++n){
      if (!trans){
        int cl = (tn + wc * 64 + n * 16 + fr) & 1023;
        float bv = dsc.bias ? dsc.bias[cl] : 0.f;
        #pragma unroll
        for (int r = 0; r < 4; ++r){
          int row = tm + wr * 128 + m * 16 + fg * 4 + r;
          float v = acc[m][n][r] + bv;
          if (dsc.of) dsc.of[(size_t)row * dsc.ld + cl] = v;
          if (dsc.ob) dsc.ob[(size_t)row * dsc.ld + cl] = f2bf(v);
        }
      } else {
        int colT = tm + wr * 128 + m * 16 + fr;             // token
        #pragma unroll
        for (int r = 0; r < 4; ++r){
          int dl = (tn + wc * 64 + n * 16 + fg * 4 + r) & 1023;
          float v = acc[m][n][r] + (dsc.bias ? dsc.bias[dl] : 0.f);
          dsc.ob[(size_t)dl * dsc.ld + colT] = f2bf(v);
        }
      }
    }
  }
}

// ---------------- unified MFMA flash attention ----------------
// MODE 0 = local window (256, block-diagonal), 1 = sliding band (|q-j|<=256), 2 = global (32 keys).
// Block = (b, qc, h): 64 q rows. 4 waves x 16 q. K/V tiles of 64 keys.
template<int MODE>
__global__ __launch_bounds__(256) void mfma_attn(
    const unsigned short* __restrict__ Qb,
    const unsigned short* __restrict__ Kb,
    const unsigned short* __restrict__ Vtb, int ldvt,
    unsigned short* __restrict__ Out, int ldo, int ocol)
{
  __shared__ __align__(16) unsigned short Ks[64][72];
  __shared__ __align__(16) unsigned short Vs[64][72];     // XOR-swizzled within rows
  __shared__ __align__(16) unsigned short Pl[4][16][72];  // per-wave P buffer
  const int tid = threadIdx.x, lane = tid & 63, wv = tid >> 6;
  const int fr = lane & 15, fg = lane >> 4;
  const int blk = blockIdx.x;              // b*512 + qc*16 + h
  const int h  = blk & 15;
  const int qc = (blk >> 4) & 31;
  const int b  = blk >> 9;
  const int q0 = qc * 64;                  // seq-local
  const int tq0 = b * SEQ + q0;            // token index
  int jlo, ntile;
  if (MODE == 0){ jlo = (qc >> 2) << 8; ntile = 4; }
  else if (MODE == 1){
    jlo = q0 - 256 < 0 ? 0 : q0 - 256;
    int jhi = q0 + 320 > SEQ ? SEQ : q0 + 320;
    ntile = (jhi - jlo) >> 6;
  } else { jlo = 0; ntile = 1; }
  const int ktok0 = (MODE == 2) ? b * 32 : b * SEQ;

  s16x8 qf[2];
  {
    const size_t qrow = (size_t)(tq0 + wv * 16 + fr) * DIM + h * DK;
    qf[0] = *(const s16x8*)&Qb[qrow + fg * 8];
    qf[1] = *(const s16x8*)&Qb[qrow + 32 + fg * 8];
  }
  f32x4 of[4];
  #pragma unroll
  for (int dt = 0; dt < 4; ++dt) of[dt] = (f32x4){0.f, 0.f, 0.f, 0.f};
  f32x4 m4 = (f32x4){MINIT, MINIT, MINIT, MINIT};
  f32x4 l4 = (f32x4){0.f, 0.f, 0.f, 0.f};

  for (int t = 0; t < ntile; ++t){
    const int jb = jlo + t * 64;
    __syncthreads();
    #pragma unroll
    for (int p = 0; p < 2; ++p){
      int idx = p * 256 + tid;
      int row = idx >> 3, c8 = idx & 7;
      *(i32x4*)&Ks[row][c8 * 8] =
          *(const i32x4*)&Kb[(size_t)(ktok0 + jb + row) * DIM + h * DK + c8 * 8];
      i32x4 v = *(const i32x4*)&Vtb[(size_t)(h * DK + row) * ldvt + ktok0 + jb + c8 * 8];
      *(i32x4*)((char*)Vs + row * 144 + ((c8 * 16) ^ ((row & 7) << 4))) = v;
    }
    __syncthreads();
    f32x4 sf[4];
    #pragma unroll
    for (int t16 = 0; t16 < 4; ++t16){
      sf[t16] = (f32x4){0.f, 0.f, 0.f, 0.f};
      #pragma unroll
      for (int ks = 0; ks < 2; ++ks){
        s16x8 kf = *(const s16x8*)&Ks[t16 * 16 + fr][ks * 32 + fg * 8];
        sf[t16] = __builtin_amdgcn_mfma_f32_16x16x32_bf16(qf[ks], kf, sf[t16], 0, 0, 0);
      }
    }
    #pragma unroll
    for (int t16 = 0; t16 < 4; ++t16){
      int j = jb + t16 * 16 + fr;
      #pragma unroll
      for (int r = 0; r < 4; ++r){
        float v = sf[t16][r] * SCALE_F;
        bool valid = true;
        if (MODE == 1){ int dq = (q0 + wv * 16 + fg * 4 + r) - j; valid = (dq <= 256) && (dq >= -256); }
        if (MODE == 2){ valid = j < 32; }
        sf[t16][r] = valid ? v : MASKED;
      }
    }
    f32x4 mx;
    #pragma unroll
    for (int r = 0; r < 4; ++r)
      mx[r] = fmaxf(fmaxf(sf[0][r], sf[1][r]), fmaxf(sf[2][r], sf[3][r]));
    #pragma unroll
    for (int off = 1; off < 16; off <<= 1){
      #pragma unroll
      for (int r = 0; r < 4; ++r) mx[r] = fmaxf(mx[r], __shfl_xor(mx[r], off));
    }
    f32x4 sc;
    #pragma unroll
    for (int r = 0; r < 4; ++r){
      float mn = fmaxf(m4[r], mx[r]);
      sc[r] = __expf(m4[r] - mn);
      m4[r] = mn;
    }
    f32x4 sm = (f32x4){0.f, 0.f, 0.f, 0.f};
    #pragma unroll
    for (int t16 = 0; t16 < 4; ++t16){
      #pragma unroll
      for (int r = 0; r < 4; ++r){
        float e = __expf(sf[t16][r] - m4[r]);
        sm[r] += e;
        Pl[wv][fg * 4 + r][t16 * 16 + fr] = f2bf(e);
      }
    }
    #pragma unroll
    for (int off = 1; off < 16; off <<= 1){
      #pragma unroll
      for (int r = 0; r < 4; ++r) sm[r] += __shfl_xor(sm[r], off);
    }
    #pragma unroll
    for (int r = 0; r < 4; ++r) l4[r] = l4[r] * sc[r] + sm[r];
    #pragma unroll
    for (int dt = 0; dt < 4; ++dt)
      #pragma unroll
      for (int r = 0; r < 4; ++r) of[dt][r] *= sc[r];
    #pragma unroll
    for (int ks2 = 0; ks2 < 2; ++ks2){
      s16x8 pa = *(const s16x8*)&Pl[wv][fr][ks2 * 32 + fg * 8];
      #pragma unroll
      for (int dt = 0; dt < 4; ++dt){
        int d = dt * 16 + fr;
        s16x8 vf = *(const s16x8*)((char*)Vs + d * 144 + ((ks2 * 64 + fg * 16) ^ ((d & 7) << 4)));
        of[dt] = __builtin_amdgcn_mfma_f32_16x16x32_bf16(pa, vf, of[dt], 0, 0, 0);
      }
    }
  }
  #pragma unroll
  for (int dt = 0; dt < 4; ++dt){
    #pragma unroll
    for (int r = 0; r < 4; ++r){
      float val = of[dt][r] / l4[r];
      int q = tq0 + wv * 16 + fg * 4 + r;
      Out[(size_t)q * ldo + ocol + h * DK + dt * 16 + fr] = f2bf(val);
    }
  }
}

// ---------------- fused residual + LayerNorm ----------------
__global__ __launch_bounds__(256) void ln_fused(
    const float* __restrict__ x, const float* __restrict__ dlt,
    const float* __restrict__ g, const float* __restrict__ bta,
    float* __restrict__ outf, unsigned short* __restrict__ outb, int ldo)
{
  const int row = blockIdx.x;
  const int t = threadIdx.x, lane = t & 63, wv = t >> 6;
  const float* xr = x + (size_t)row * DIM;
  const float* dr = dlt + (size_t)row * DIM;
  f4 xv = *(const f4*)&xr[t * 4];
  f4 dv = *(const f4*)&dr[t * 4];
  f4 y = xv + dv;
  float s = y[0] + y[1] + y[2] + y[3];
  float ss = y[0]*y[0] + y[1]*y[1] + y[2]*y[2] + y[3]*y[3];
  #pragma unroll
  for (int off = 1; off < 64; off <<= 1){ s += __shfl_xor(s, off); ss += __shfl_xor(ss, off); }
  __shared__ float red[8];
  if (lane == 0){ red[wv] = s; red[wv + 4] = ss; }
  __syncthreads();
  float S = red[0] + red[1] + red[2] + red[3];
  float SS = red[4] + red[5] + red[6] + red[7];
  float mu = S * (1.f / DIM);
  float var = SS * (1.f / DIM) - mu * mu;
  float rs = rsqrtf(var + 1e-5f);
  f4 gv = *(const f4*)&g[t * 4];
  f4 bv = *(const f4*)&bta[t * 4];
  f4 o;
  #pragma unroll
  for (int i = 0; i < 4; ++i) o[i] = (y[i] - mu) * rs * gv[i] + bv[i];
  if (outf) *(f4*)&outf[(size_t)row * ldo + t * 4] = o;
  if (outb){
    u16x4 ob = { f2bf(o[0]), f2bf(o[1]), f2bf(o[2]), f2bf(o[3]) };
    *(u16x4*)&outb[(size_t)row * ldo + t * 4] = ob;
  }
}

// ---------------- host launch ----------------
extern "C" void kernel_launch(void* const* d_in, const int* in_sizes, int n_in,
                              void* d_out, int out_size, void* d_ws, size_t ws_size,
                              hipStream_t stream){
  (void)in_sizes; (void)n_in; (void)out_size; (void)ws_size;
  const float* x      = (const float*)d_in[0];
  const float* lq_w   = (const float*)d_in[1];  const float* lq_b  = (const float*)d_in[2];
  const float* lk_w   = (const float*)d_in[3];  const float* lk_b  = (const float*)d_in[4];
  const float* lv_w   = (const float*)d_in[5];  const float* lv_b  = (const float*)d_in[6];
  const float* gq_w   = (const float*)d_in[7];  const float* gq_b  = (const float*)d_in[8];
  const float* gk_w   = (const float*)d_in[9];  const float* gk_b  = (const float*)d_in[10];
  const float* gv_w   = (const float*)d_in[11]; const float* gv_b  = (const float*)d_in[12];
  const float* ho_w   = (const float*)d_in[13]; const float* ho_b  = (const float*)d_in[14];
  const float* hln_g  = (const float*)d_in[15]; const float* hln_b = (const float*)d_in[16];
  const float* sq_w   = (const float*)d_in[17]; const float* sq_b  = (const float*)d_in[18];
  const float* sk_w   = (const float*)d_in[19]; const float* sk_b  = (const float*)d_in[20];
  const float* sv_w   = (const float*)d_in[21]; const float* sv_b  = (const float*)d_in[22];
  const float* so_w   = (const float*)d_in[23]; const float* so_b  = (const float*)d_in[24];
  const float* cb_w   = (const float*)d_in[25]; const float* cb_b  = (const float*)d_in[26];
  const float* ln_g   = (const float*)d_in[27]; const float* ln_b  = (const float*)d_in[28];

  const size_t M = (size_t)BATCH * SEQ;      // 4096
  const size_t W1 = (size_t)DIM * DIM;       // one 1024x1024 weight (elements)
  char* ws = (char*)d_ws;
  size_t off = 0;
  auto alloc = [&](size_t bytes) -> void* {
    void* p = ws + off; off += (bytes + 255) & ~(size_t)255; return p;
  };
  unsigned short* xb    = (unsigned short*)alloc(M * DIM * 2);
  unsigned short* wt_s  = (unsigned short*)alloc(3 * W1 * 2);   // [sq|sk|sv]
  unsigned short* wt_lg = (unsigned short*)alloc(4 * W1 * 2);   // [lq|lk|lv|gq]
  unsigned short* wt_g2 = (unsigned short*)alloc(2 * W1 * 2);   // [gk|gv]
  unsigned short* wt_so = (unsigned short*)alloc(W1 * 2);
  unsigned short* wt_ho = (unsigned short*)alloc(2 * W1 * 2);
  unsigned short* wt_cb = (unsigned short*)alloc(2 * W1 * 2);
  unsigned short* gcb   = (unsigned short*)alloc((size_t)128 * DIM * 2);
  unsigned short* qb    = (unsigned short*)alloc(M * DIM * 2);
  unsigned short* kb    = (unsigned short*)alloc(M * DIM * 2);
  unsigned short* vtb   = (unsigned short*)alloc(M * DIM * 2);   // [1024][4096]
  unsigned short* qg    = (unsigned short*)alloc(M * DIM * 2);
  unsigned short* gkb   = (unsigned short*)alloc((size_t)128 * DIM * 2);
  unsigned short* vtg   = (unsigned short*)alloc((size_t)128 * DIM * 2); // [1024][128]
  unsigned short* satt  = (unsigned short*)alloc(M * DIM * 2);
  unsigned short* hcat  = (unsigned short*)alloc(M * 2 * DIM * 2);
  unsigned short* ccat  = (unsigned short*)alloc(M * 2 * DIM * 2);
  float* Af             = (float*)alloc(M * DIM * 4);

  dim3 b256(256);
  dim3 b512(512);
  // ---- casts / transposes ----
  cast_bf16_kernel<<<dim3((M * DIM) / 1024), b256, 0, stream>>>(x, xb, (int)(M * DIM));
  {
    TCP p1 = {};
    const float* ws_[10] = {sq_w, sk_w, sv_w, lq_w, lk_w, lv_w, gq_w, gk_w, gv_w, so_w};
    unsigned short* wts_[10] = {wt_s, wt_s + W1, wt_s + 2 * W1,
                                wt_lg, wt_lg + W1, wt_lg + 2 * W1, wt_lg + 3 * W1,
                                wt_g2, wt_g2 + W1, wt_so};
    for (int i = 0; i < 10; ++i){ p1.w[i] = ws_[i]; p1.wt[i] = wts_[i]; }
    transpose_cast_b<<<dim3(32, 32, 10), b256, 0, stream>>>(p1, DIM);
    TCP p2 = {};
    p2.w[0] = ho_w; p2.wt[0] = wt_ho;
    p2.w[1] = cb_w; p2.wt[1] = wt_cb;
    transpose_cast_b<<<dim3(32, 64, 2), b256, 0, stream>>>(p2, 2 * DIM);
  }
  gc_extract<<<dim3(128), b256, 0, stream>>>(x, gcb);

  dim3 attn_grid(1024);
  auto mk = [&](unsigned short* ob, float* of, const float* bias, int ld, int tr) -> GOut {
    GOut g; g.ob = ob; g.of = of; g.bias = bias; g.ld = ld; g.tr = tr; return g;
  };

  // ---- sliding branch: fused QKV (N=3072, 256-tile, grid 12x16) ----
  {
    GOuts ds = {};
    ds.d[0] = mk(qb,  nullptr, sq_b, DIM, 0);
    ds.d[1] = mk(kb,  nullptr, sk_b, DIM, 0);
    ds.d[2] = mk(vtb, nullptr, sv_b, (int)M, 1);
    gemm256<<<dim3(12, 16), b512, 0, stream>>>(xb, wt_s, ds, DIM);
  }
  mfma_attn<1><<<attn_grid, b256, 0, stream>>>(qb, kb, vtb, (int)M, satt, DIM, 0);

  // ---- local + gq: fused (N=4096, 256-tile, grid 16x16) ----
  {
    GOuts ds = {};
    ds.d[0] = mk(qb,  nullptr, lq_b, DIM, 0);
    ds.d[1] = mk(kb,  nullptr, lk_b, DIM, 0);
    ds.d[2] = mk(vtb, nullptr, lv_b, (int)M, 1);
    ds.d[3] = mk(qg,  nullptr, gq_b, DIM, 0);
    gemm256<<<dim3(16, 16), b512, 0, stream>>>(xb, wt_lg, ds, DIM);
  }
  // ---- s_out projection (N=1024, BN=64 -> 512 blocks = 2/CU) ----
  {
    GOuts ds = {};
    ds.d[0] = mk(ccat + 1024, nullptr, so_b, 2 * DIM, 0);
    gemm_bf16<64><<<dim3(16, 32), b256, 0, stream>>>(satt, wt_so, ds, DIM);
  }
  mfma_attn<0><<<attn_grid, b256, 0, stream>>>(qb, kb, vtb, (int)M, hcat, 2 * DIM, 0);

  // ---- global branch: fused gk+gv (M=128, N=2048) ----
  {
    GOuts ds = {};
    ds.d[0] = mk(gkb, nullptr, gk_b, DIM, 0);
    ds.d[1] = mk(vtg, nullptr, gv_b, 128, 1);
    gemm_bf16<128><<<dim3(16, 1), b256, 0, stream>>>(gcb, wt_g2, ds, DIM);
  }
  mfma_attn<2><<<attn_grid, b256, 0, stream>>>(qg, gkb, vtg, 128, hcat, 2 * DIM, 1024);

  // ---- h_out projection + LN1 ----
  {
    GOuts ds = {};
    ds.d[0] = mk(nullptr, Af, ho_b, DIM, 0);
    gemm_bf16<64><<<dim3(16, 32), b256, 0, stream>>>(hcat, wt_ho, ds, 2 * DIM);
  }
  ln_fused<<<dim3((int)M), b256, 0, stream>>>(x, Af, hln_g, hln_b, nullptr, ccat, 2 * DIM);

  // ---- combine + LN2 ----
  {
    GOuts ds = {};
    ds.d[0] = mk(nullptr, Af, cb_b, DIM, 0);
    gemm_bf16<64><<<dim3(16, 32), b256, 0, stream>>>(ccat, wt_cb, ds, 2 * DIM);
  }
  ln_fused<<<dim3((int)M), b256, 0, stream>>>(x, Af, ln_g, ln_b, (float*)d_out, nullptr, DIM);
}